// Round 5
// baseline (7172.095 us; speedup 1.0000x reference)
//
#include <hip/hip_runtime.h>
#include <hip/hip_bf16.h>
#include <float.h>

#define SEQ   8192
#define INW   180
#define HID   64
#define G4    256   // 4*HID
#define OUTW  10
#define XW    318   // 10 + 64 + 180 + 64

typedef float f32x4 __attribute__((ext_vector_type(4)));

__device__ __forceinline__ float frcp(float x)   { return __builtin_amdgcn_rcpf(x); }
__device__ __forceinline__ float tanhf_f(float x){ return 1.0f - 2.0f * frcp(1.0f + __expf(2.0f * x)); }
// unified gate activation: sigmoid for i/f/o, tanh (=2*sig(2x)-1) for g
__device__ __forceinline__ float gate_act(float x, bool isg) {
    float xx = isg ? 2.0f * x : x;
    float s  = frcp(1.0f + __expf(-xx));
    return isg ? 2.0f * s - 1.0f : s;
}

// DPP quad_perm broadcast — pure VALU
template<int CTRL>
__device__ __forceinline__ float dpp_bcast(float x) {
    return __int_as_float(__builtin_amdgcn_update_dpp(
        0, __float_as_int(x), CTRL, 0xF, 0xF, true));
}

#define PIN4(v) asm volatile("" : "+v"((v).x), "+v"((v).y), "+v"((v).z), "+v"((v).w))

// ---------------------------------------------------------------------------
// Kernel 1: pre[s][t] = x[s] @ Wih0[row(t)].T + bih0[row(t)] + bhh0[row(t)]
// row(t) = (t&3)*64 + (t>>2)  — unit-major permutation used by k_lstm_seq
// ---------------------------------------------------------------------------
#define PRE_TS 16
__global__ __launch_bounds__(256) void k_precompute(
    const float* __restrict__ x,      // [SEQ][INW]
    const float* __restrict__ Wih0,   // [G4][INW]
    const float* __restrict__ bih0,
    const float* __restrict__ bhh0,
    float* __restrict__ pre)          // [SEQ][G4] (permuted rows)
{
    __shared__ float xT[INW][PRE_TS];
    const int t  = threadIdx.x;
    const int rr = (t & 3) * 64 + (t >> 2);
    const int s0 = blockIdx.x * PRE_TS;
    for (int i = t; i < PRE_TS * INW; i += 256) {
        int s = i / INW, k = i % INW;
        xT[k][s] = x[s0 * INW + i];
    }
    __syncthreads();
    float acc[PRE_TS];
    const float b = bih0[rr] + bhh0[rr];
#pragma unroll
    for (int s = 0; s < PRE_TS; ++s) acc[s] = b;
    for (int k = 0; k < INW; ++k) {
        float w = Wih0[rr * INW + k];
#pragma unroll
        for (int s = 0; s < PRE_TS; ++s) acc[s] += w * xT[k][s];
    }
#pragma unroll
    for (int s = 0; s < PRE_TS; ++s) pre[(s0 + s) * G4 + t] = acc[s];
}

// ---------------------------------------------------------------------------
// Kernel 2: serial 2-layer LSTM, wave-specialized + lane-pair row split.
// ONE block, 1024 threads (16 waves, 4/SIMD). SEQ+1 barrier intervals.
//   grp=t>>9: 0 = layer0 (intervals 0..SEQ-1), 1 = layer1 (intervals 1..SEQ)
//   i9=t&511, q=i9>>1 (row 0..255), half=i9&1, g=q&3, u=q>>2, r=g*64+u.
//   layer0 thread: 8 weight quads (cols 32*half..); layer1: 16 quads
//   (half0 = Wih1 row vs h0, half1 = Whh1 row vs h1).
//   Pair-sum via shfl_xor(1); 8-lane gate group [i,i,f,f,g,g,o,o] combined
//   via 2 DPP quad_perm + 2 shfl_xor(4) + selects.
// ---------------------------------------------------------------------------
__global__ __launch_bounds__(1024) __attribute__((amdgpu_waves_per_eu(4, 4)))
void k_lstm_seq(
    const float* __restrict__ pre,    // [SEQ][G4] permuted
    const float* __restrict__ Whh0,   // [G4][HID]
    const float* __restrict__ Wih1,   // [G4][HID]
    const float* __restrict__ Whh1,   // [G4][HID]
    const float* __restrict__ bih1,
    const float* __restrict__ bhh1,
    float* __restrict__ oldh,         // [SEQ][HID] (h0 at START of step s)
    float* __restrict__ h1h)          // [SEQ][HID] (h1 after step s)
{
    const int t    = threadIdx.x;
    const int grp  = t >> 9;
    const int i9   = t & 511;
    const int q    = i9 >> 1;
    const int half = i9 & 1;
    const int g    = q & 3;           // gate: 0=i 1=f 2=g 3=o
    const int u    = q >> 2;          // unit 0..63
    const int r    = g * 64 + u;      // weight/bias row
    const int lane = t & 63;
    const bool isg = (g == 2);
    const bool hi4 = (lane & 4) != 0;

    __shared__ f32x4 h0v[2][16];      // h0 broadcast, double-buffered
    __shared__ f32x4 h1v[2][16];      // h1 broadcast, double-buffered
    if (t < 16) {
        f32x4 z = {0.f, 0.f, 0.f, 0.f};
        h0v[0][t] = z; h0v[1][t] = z; h1v[0][t] = z; h1v[1][t] = z;
    }
    if (t < 64) oldh[t] = 0.0f;
    __syncthreads();

    if (grp == 0) {
        // ========== layer-0: H0[s+1] = cell(x(s), H0[s], c0) ==========
        f32x4 w[8];
        {
            const f32x4* W = (const f32x4*)(Whh0 + r * HID + 32 * half);
#pragma unroll
            for (int j = 0; j < 8; ++j) w[j] = W[j];
#pragma unroll
            for (int j = 0; j < 8; ++j) PIN4(w[j]);
        }
        float c0 = 0.f;
        float preval = pre[q];        // pair lanes load same addr (broadcast)
        for (int s = 0; s <= SEQ; ++s) {
            if (s < SEQ) {
                const int p = s & 1, pn = p ^ 1;
                const int sn = (s + 1 < SEQ) ? (s + 1) : s;
                float prenext = pre[sn * G4 + q];

                float va = half ? 0.0f : preval, vb = 0.f;
                const f32x4* H = (const f32x4*)&h0v[p][half * 8];
#pragma unroll
                for (int j = 0; j < 8; ++j) {
                    f32x4 h = H[j], ww = w[j];
                    va = fmaf(ww.x, h.x, va); vb = fmaf(ww.y, h.y, vb);
                    va = fmaf(ww.z, h.z, va); vb = fmaf(ww.w, h.w, vb);
                }
                float ap = va + vb;
                ap += __shfl_xor(ap, 1);                 // pair sum -> full dot
                float a  = gate_act(ap, isg);
                float p0 = dpp_bcast<0x00>(a), p2 = dpp_bcast<0xAA>(a);
                float s0 = __shfl_xor(p0, 4), s2 = __shfl_xor(p2, 4);
                float i_ = hi4 ? s0 : p0, f_ = hi4 ? s2 : p2;
                float g_ = hi4 ? p0 : s0, o_ = hi4 ? p2 : s2;
                c0 = fmaf(f_, c0, i_ * g_);
                float h0n = o_ * tanhf_f(c0);
                if ((i9 & 7) == 0) ((float*)&h0v[pn][0])[u] = h0n;
                if ((i9 & 7) == 2 && s + 1 < SEQ) oldh[(s + 1) * HID + u] = h0n;
                preval = prenext;
            }
            asm volatile("s_waitcnt lgkmcnt(0)" ::: "memory");
            __builtin_amdgcn_s_barrier();
            asm volatile("" ::: "memory");
        }
    } else {
        // ========== layer-1: Y[s-1] = cell(H0[s], Y[s-2], c1) ==========
        f32x4 w[16];
        {
            const float* Wb = half ? (Whh1 + r * HID) : (Wih1 + r * HID);
            const f32x4* W  = (const f32x4*)Wb;
#pragma unroll
            for (int j = 0; j < 16; ++j) w[j] = W[j];
#pragma unroll
            for (int j = 0; j < 16; ++j) PIN4(w[j]);
        }
        const float b1 = bih1[r] + bhh1[r];
        float c1 = 0.f;
        for (int s = 0; s <= SEQ; ++s) {
            if (s >= 1) {
                const int p = s & 1, pn = p ^ 1;

                float va = half ? 0.0f : b1, vb = 0.f, vc = 0.f, vd = 0.f;
                const f32x4* H = half ? (const f32x4*)&h1v[p][0]
                                      : (const f32x4*)&h0v[p][0];
#pragma unroll
                for (int j = 0; j < 16; j += 2) {
                    f32x4 h0 = H[j],   w0 = w[j];
                    f32x4 h1 = H[j+1], w1 = w[j+1];
                    va = fmaf(w0.x, h0.x, va); vb = fmaf(w0.y, h0.y, vb);
                    va = fmaf(w0.z, h0.z, va); vb = fmaf(w0.w, h0.w, vb);
                    vc = fmaf(w1.x, h1.x, vc); vd = fmaf(w1.y, h1.y, vd);
                    vc = fmaf(w1.z, h1.z, vc); vd = fmaf(w1.w, h1.w, vd);
                }
                float ap = (va + vb) + (vc + vd);
                ap += __shfl_xor(ap, 1);                 // pair sum
                float a  = gate_act(ap, isg);
                float p0 = dpp_bcast<0x00>(a), p2 = dpp_bcast<0xAA>(a);
                float s0 = __shfl_xor(p0, 4), s2 = __shfl_xor(p2, 4);
                float i_ = hi4 ? s0 : p0, f_ = hi4 ? s2 : p2;
                float g_ = hi4 ? p0 : s0, o_ = hi4 ? p2 : s2;
                c1 = fmaf(f_, c1, i_ * g_);
                float h1n = o_ * tanhf_f(c1);            // Y[s-1]
                if ((i9 & 7) == 0) ((float*)&h1v[pn][0])[u] = h1n;
                if ((i9 & 7) == 2) h1h[(s - 1) * HID + u] = h1n;
            }
            asm volatile("s_waitcnt lgkmcnt(0)" ::: "memory");
            __builtin_amdgcn_s_barrier();
            asm volatile("" ::: "memory");
        }
    }
}

// ---------------------------------------------------------------------------
// Kernel 3a/3b: column-wise min/max of oldh (64 cols x 8192 rows)
// ---------------------------------------------------------------------------
__global__ __launch_bounds__(256) void k_minmax1(
    const float* __restrict__ oldh, float* __restrict__ pmn, float* __restrict__ pmx)
{
    const int t = threadIdx.x, b = blockIdx.x;
    float vmn = FLT_MAX, vmx = -FLT_MAX;
    for (int i = t; i < 128 * HID; i += 256) {
        float v = oldh[b * 128 * HID + i];
        vmn = fminf(vmn, v); vmx = fmaxf(vmx, v);
    }
    __shared__ float smn[256], smx[256];
    smn[t] = vmn; smx[t] = vmx;
    __syncthreads();
    if (t < 64) {
        float m0 = fminf(fminf(smn[t], smn[t + 64]), fminf(smn[t + 128], smn[t + 192]));
        float m1 = fmaxf(fmaxf(smx[t], smx[t + 64]), fmaxf(smx[t + 128], smx[t + 192]));
        pmn[b * 64 + t] = m0; pmx[b * 64 + t] = m1;
    }
}

__global__ __launch_bounds__(256) void k_minmax2(
    const float* __restrict__ pmn, const float* __restrict__ pmx,
    float* __restrict__ mn, float* __restrict__ mx)
{
    const int t = threadIdx.x, col = t & 63, chunk = t >> 6;
    float vmn = FLT_MAX, vmx = -FLT_MAX;
    for (int r = chunk * 16; r < chunk * 16 + 16; ++r) {
        vmn = fminf(vmn, pmn[r * 64 + col]);
        vmx = fmaxf(vmx, pmx[r * 64 + col]);
    }
    __shared__ float smn[256], smx[256];
    smn[t] = vmn; smx[t] = vmx;
    __syncthreads();
    if (t < 64) {
        mn[t] = fminf(fminf(smn[t], smn[t + 64]), fminf(smn[t + 128], smn[t + 192]));
        mx[t] = fmaxf(fmaxf(smx[t], smx[t + 64]), fmaxf(smx[t + 128], smx[t + 192]));
    }
}

// ---------------------------------------------------------------------------
// Kernel 4: per-row head + HPM MLP fwd + closed-form VJP. 1 wave per row.
// ---------------------------------------------------------------------------
__global__ __launch_bounds__(256) void k_finalize(
    const float* __restrict__ h1h, const float* __restrict__ oldh,
    const float* __restrict__ x,
    const float* __restrict__ Wlin, const float* __restrict__ blin,
    const float* __restrict__ Wh1,  const float* __restrict__ bh1,
    const float* __restrict__ Wh2,  const float* __restrict__ bh2,
    const float* __restrict__ mn,   const float* __restrict__ mx,
    float* __restrict__ dout)
{
    float* out_o = dout;                          // [SEQ][10]
    float* out_F = dout + SEQ * OUTW;             // [SEQ][180]
    float* out_A = dout + SEQ * (OUTW + INW);     // [SEQ][318]

    const int wave = threadIdx.x >> 6, lane = threadIdx.x & 63;
    const int row  = blockIdx.x * 4 + wave;

    __shared__ float Xs[4][XW + 2];
    __shared__ float h1sh[4][HID];

    h1sh[wave][lane] = h1h[row * HID + lane];
    float mnv = mn[lane], mxv = mx[lane];
    Xs[wave][254 + lane] = (oldh[row * HID + lane] - mnv) * frcp(mxv - mnv + 1e-6f);
    Xs[wave][10 + lane]  = 0.0f;
    for (int c = lane; c < INW; c += 64) Xs[wave][74 + c] = x[row * INW + c];
    __syncthreads();

    if (lane < OUTW) {
        float o = blin[lane];
#pragma unroll
        for (int k = 0; k < HID; ++k) o += Wlin[lane * HID + k] * h1sh[wave][k];
        Xs[wave][lane] = o;
        out_o[row * OUTW + lane] = o;
    }
    __syncthreads();

    float z0 = 0.f, z1 = 0.f, s0 = 0.f, s1 = 0.f;
    for (int c = lane; c < XW; c += 64) {
        float xv = Xs[wave][c];
        z0 += xv * Wh1[c];
        z1 += xv * Wh1[XW + c];
    }
    for (int j = lane; j < INW; j += 64) {
        s0 += Wh2[j * 2 + 0];
        s1 += Wh2[j * 2 + 1];
    }
#pragma unroll
    for (int off = 32; off; off >>= 1) {
        z0 += __shfl_xor(z0, off); z1 += __shfl_xor(z1, off);
        s0 += __shfl_xor(s0, off); s1 += __shfl_xor(s1, off);
    }
    const float t0 = tanhf_f(z0 + bh1[0]);
    const float t1 = tanhf_f(z1 + bh1[1]);
    const float a0 = -s0 * (1.0f - t0 * t0);
    const float a1 = -s1 * (1.0f - t1 * t1);

    for (int c = lane; c < INW; c += 64)
        out_F[row * INW + c] = -(t0 * Wh2[c * 2 + 0] + t1 * Wh2[c * 2 + 1] + bh2[c]);
    for (int c = lane; c < XW; c += 64)
        out_A[row * XW + c] = a0 * Wh1[c] + a1 * Wh1[XW + c];
}

// ---------------------------------------------------------------------------
extern "C" void kernel_launch(void* const* d_in, const int* in_sizes, int n_in,
                              void* d_out, int out_size, void* d_ws, size_t ws_size,
                              hipStream_t stream)
{
    const float* input = (const float*)d_in[0];
    const float* Wih0  = (const float*)d_in[1];
    const float* Whh0  = (const float*)d_in[2];
    const float* bih0  = (const float*)d_in[3];
    const float* bhh0  = (const float*)d_in[4];
    const float* Wih1  = (const float*)d_in[5];
    const float* Whh1  = (const float*)d_in[6];
    const float* bih1  = (const float*)d_in[7];
    const float* bhh1  = (const float*)d_in[8];
    const float* Wlin  = (const float*)d_in[9];
    const float* blin  = (const float*)d_in[10];
    const float* Wh1   = (const float*)d_in[11];
    const float* bh1   = (const float*)d_in[12];
    const float* Wh2   = (const float*)d_in[13];
    const float* bh2   = (const float*)d_in[14];

    float* ws   = (float*)d_ws;
    float* pre  = ws;                         // SEQ*G4
    float* oldh = pre  + SEQ * G4;            // SEQ*HID
    float* h1h  = oldh + SEQ * HID;           // SEQ*HID
    float* pmn  = h1h  + SEQ * HID;           // 64*64
    float* pmx  = pmn  + 64 * 64;             // 64*64
    float* mn   = pmx  + 64 * 64;             // 64
    float* mx   = mn   + 64;                  // 64
    float* out  = (float*)d_out;

    hipLaunchKernelGGL(k_precompute, dim3(SEQ / PRE_TS), dim3(256), 0, stream,
                       input, Wih0, bih0, bhh0, pre);
    hipLaunchKernelGGL(k_lstm_seq, dim3(1), dim3(1024), 0, stream,
                       pre, Whh0, Wih1, Whh1, bih1, bhh1, oldh, h1h);
    hipLaunchKernelGGL(k_minmax1, dim3(64), dim3(256), 0, stream, oldh, pmn, pmx);
    hipLaunchKernelGGL(k_minmax2, dim3(1), dim3(256), 0, stream, pmn, pmx, mn, mx);
    hipLaunchKernelGGL(k_finalize, dim3(SEQ / 4), dim3(256), 0, stream,
                       h1h, oldh, input, Wlin, blin, Wh1, bh1, Wh2, bh2, mn, mx, out);
}

// Round 6
// 7010.927 us; speedup vs baseline: 1.0230x; 1.0230x over previous
//
#include <hip/hip_runtime.h>
#include <hip/hip_bf16.h>
#include <float.h>

#define SEQ   8192
#define INW   180
#define HID   64
#define G4    256   // 4*HID
#define OUTW  10
#define XW    318   // 10 + 64 + 180 + 64

typedef float f32x4 __attribute__((ext_vector_type(4)));

__device__ __forceinline__ float frcp(float x)   { return __builtin_amdgcn_rcpf(x); }
__device__ __forceinline__ float tanhf_f(float x){ return 1.0f - 2.0f * frcp(1.0f + __expf(2.0f * x)); }
// unified gate activation: sigmoid for i/f/o, tanh (=2*sig(2x)-1) for g
__device__ __forceinline__ float gate_act(float x, bool isg) {
    float xx = isg ? 2.0f * x : x;
    float s  = frcp(1.0f + __expf(-xx));
    return isg ? 2.0f * s - 1.0f : s;
}

// DPP quad_perm broadcast — pure VALU
template<int CTRL>
__device__ __forceinline__ float dpp_bcast(float x) {
    return __int_as_float(__builtin_amdgcn_update_dpp(
        0, __float_as_int(x), CTRL, 0xF, 0xF, true));
}

// ---------------------------------------------------------------------------
// Kernel 1: pre[s][t] = x[s] @ Wih0[row(t)].T + bih0[row(t)] + bhh0[row(t)]
// row(t) = (t&3)*64 + (t>>2)  — unit-major permutation used by k_lstm_seq
// ---------------------------------------------------------------------------
#define PRE_TS 16
__global__ __launch_bounds__(256) void k_precompute(
    const float* __restrict__ x,      // [SEQ][INW]
    const float* __restrict__ Wih0,   // [G4][INW]
    const float* __restrict__ bih0,
    const float* __restrict__ bhh0,
    float* __restrict__ pre)          // [SEQ][G4] (permuted rows)
{
    __shared__ float xT[INW][PRE_TS];
    const int t  = threadIdx.x;
    const int rr = (t & 3) * 64 + (t >> 2);
    const int s0 = blockIdx.x * PRE_TS;
    for (int i = t; i < PRE_TS * INW; i += 256) {
        int s = i / INW, k = i % INW;
        xT[k][s] = x[s0 * INW + i];
    }
    __syncthreads();
    float acc[PRE_TS];
    const float b = bih0[rr] + bhh0[rr];
#pragma unroll
    for (int s = 0; s < PRE_TS; ++s) acc[s] = b;
    for (int k = 0; k < INW; ++k) {
        float w = Wih0[rr * INW + k];
#pragma unroll
        for (int s = 0; s < PRE_TS; ++s) acc[s] += w * xT[k][s];
    }
#pragma unroll
    for (int s = 0; s < PRE_TS; ++s) pre[(s0 + s) * G4 + t] = acc[s];
}

// ---------------------------------------------------------------------------
// Kernel 2: serial 2-layer LSTM, wave-specialized layer pipeline.
// ONE block, 768 threads (12 waves, 3/SIMD). SEQ+1 barrier intervals.
//   t <  256:           layer0, intervals 0..SEQ-1:  H0[s+1]=cell(x(s),H0[s],c0)
//                       full Whh0 row in 16 reg quads, DPP quad gate-combine.
//   256 <= t < 768:     layer1, intervals 1..SEQ:    Y[s-1]=cell(H0[s],Y[s-2],c1)
//                       lane-pair matrix split: half0=Wih1 row vs h0,
//                       half1=Whh1 row vs h1 (16 reg quads each);
//                       pair-sum shfl_xor(1), 8-lane gate combine.
// amdgpu_waves_per_eu(3,3): pins the allocator's occupancy target to the
// launched occupancy (170-VGPR budget) so the weight quads stay register-
// resident instead of being remat-reloaded from memory every step.
// ---------------------------------------------------------------------------
__global__ __launch_bounds__(768) __attribute__((amdgpu_waves_per_eu(3, 3)))
void k_lstm_seq(
    const float* __restrict__ pre,    // [SEQ][G4] permuted
    const float* __restrict__ Whh0,   // [G4][HID]
    const float* __restrict__ Wih1,   // [G4][HID]
    const float* __restrict__ Whh1,   // [G4][HID]
    const float* __restrict__ bih1,
    const float* __restrict__ bhh1,
    float* __restrict__ oldh,         // [SEQ][HID] (h0 at START of step s)
    float* __restrict__ h1h)          // [SEQ][HID] (h1 after step s)
{
    const int t = threadIdx.x;

    __shared__ f32x4 h0v[2][16];      // h0 broadcast, double-buffered
    __shared__ f32x4 h1v[2][16];      // h1 broadcast, double-buffered
    if (t < 16) {
        f32x4 z = {0.f, 0.f, 0.f, 0.f};
        h0v[0][t] = z; h0v[1][t] = z; h1v[0][t] = z; h1v[1][t] = z;
    }
    if (t < 64) oldh[t] = 0.0f;
    __syncthreads();

    if (t < 256) {
        // ========== layer-0: full row, DPP quad combine (R4-verified) =====
        const int q    = t;
        const int g    = q & 3;       // gate: 0=i 1=f 2=g 3=o
        const int u    = q >> 2;      // unit
        const int r    = g * 64 + u;  // weight row
        const bool isg = (g == 2);

        f32x4 w0[16];
        {
            const f32x4* W0 = (const f32x4*)(Whh0 + r * HID);
#pragma unroll
            for (int j = 0; j < 16; ++j) w0[j] = W0[j];
        }
        float c0 = 0.f;
        float preval = pre[q];
        for (int s = 0; s <= SEQ; ++s) {
            if (s < SEQ) {
                const int p = s & 1, pn = p ^ 1;
                const int sn = (s + 1 < SEQ) ? (s + 1) : s;
                float prenext = pre[sn * G4 + q];

                float va = preval, vb = 0.f, vc = 0.f, vd = 0.f;
                const f32x4* H = (const f32x4*)&h0v[p][0];
#pragma unroll
                for (int j = 0; j < 16; j += 2) {
                    f32x4 h0 = H[j],   x0 = w0[j];
                    f32x4 h1 = H[j+1], x1 = w0[j+1];
                    va = fmaf(x0.x, h0.x, va); vb = fmaf(x0.y, h0.y, vb);
                    va = fmaf(x0.z, h0.z, va); vb = fmaf(x0.w, h0.w, vb);
                    vc = fmaf(x1.x, h1.x, vc); vd = fmaf(x1.y, h1.y, vd);
                    vc = fmaf(x1.z, h1.z, vc); vd = fmaf(x1.w, h1.w, vd);
                }
                float a  = gate_act((va + vb) + (vc + vd), isg);
                float ai = dpp_bcast<0x00>(a);
                float af = dpp_bcast<0x55>(a);
                float ag = dpp_bcast<0xAA>(a);
                float ao = dpp_bcast<0xFF>(a);
                c0 = fmaf(af, c0, ai * ag);
                float h0n = ao * tanhf_f(c0);
                if (g == 0) ((float*)&h0v[pn][0])[u] = h0n;
                if (g == 1 && s + 1 < SEQ) oldh[(s + 1) * HID + u] = h0n;
                preval = prenext;
            }
            asm volatile("s_waitcnt lgkmcnt(0)" ::: "memory");
            __builtin_amdgcn_s_barrier();
            asm volatile("" ::: "memory");
        }
    } else {
        // ========== layer-1: lane-pair matrix split (R5-verified) =========
        const int i9   = t - 256;     // 0..511
        const int q    = i9 >> 1;     // row 0..255
        const int half = i9 & 1;      // 0: Wih1 vs h0, 1: Whh1 vs h1
        const int g    = q & 3;
        const int u    = q >> 2;
        const int r    = g * 64 + u;
        const int lane = t & 63;
        const bool isg = (g == 2);
        const bool hi4 = (lane & 4) != 0;

        f32x4 w[16];
        {
            const float* Wb = half ? (Whh1 + r * HID) : (Wih1 + r * HID);
            const f32x4* W  = (const f32x4*)Wb;
#pragma unroll
            for (int j = 0; j < 16; ++j) w[j] = W[j];
        }
        const float b1 = bih1[r] + bhh1[r];
        float c1 = 0.f;
        for (int s = 0; s <= SEQ; ++s) {
            if (s >= 1) {
                const int p = s & 1, pn = p ^ 1;

                float va = half ? 0.0f : b1, vb = 0.f, vc = 0.f, vd = 0.f;
                const f32x4* H = half ? (const f32x4*)&h1v[p][0]
                                      : (const f32x4*)&h0v[p][0];
#pragma unroll
                for (int j = 0; j < 16; j += 2) {
                    f32x4 h0 = H[j],   x0 = w[j];
                    f32x4 h1 = H[j+1], x1 = w[j+1];
                    va = fmaf(x0.x, h0.x, va); vb = fmaf(x0.y, h0.y, vb);
                    va = fmaf(x0.z, h0.z, va); vb = fmaf(x0.w, h0.w, vb);
                    vc = fmaf(x1.x, h1.x, vc); vd = fmaf(x1.y, h1.y, vd);
                    vc = fmaf(x1.z, h1.z, vc); vd = fmaf(x1.w, h1.w, vd);
                }
                float ap = (va + vb) + (vc + vd);
                ap += __shfl_xor(ap, 1);                 // pair sum
                float a  = gate_act(ap, isg);
                float p0 = dpp_bcast<0x00>(a), p2 = dpp_bcast<0xAA>(a);
                float s0 = __shfl_xor(p0, 4), s2 = __shfl_xor(p2, 4);
                float i_ = hi4 ? s0 : p0, f_ = hi4 ? s2 : p2;
                float g_ = hi4 ? p0 : s0, o_ = hi4 ? p2 : s2;
                c1 = fmaf(f_, c1, i_ * g_);
                float h1n = o_ * tanhf_f(c1);            // Y[s-1]
                if ((i9 & 7) == 0) ((float*)&h1v[pn][0])[u] = h1n;
                if ((i9 & 7) == 2) h1h[(s - 1) * HID + u] = h1n;
            }
            asm volatile("s_waitcnt lgkmcnt(0)" ::: "memory");
            __builtin_amdgcn_s_barrier();
            asm volatile("" ::: "memory");
        }
    }
}

// ---------------------------------------------------------------------------
// Kernel 3a/3b: column-wise min/max of oldh (64 cols x 8192 rows)
// ---------------------------------------------------------------------------
__global__ __launch_bounds__(256) void k_minmax1(
    const float* __restrict__ oldh, float* __restrict__ pmn, float* __restrict__ pmx)
{
    const int t = threadIdx.x, b = blockIdx.x;
    float vmn = FLT_MAX, vmx = -FLT_MAX;
    for (int i = t; i < 128 * HID; i += 256) {
        float v = oldh[b * 128 * HID + i];
        vmn = fminf(vmn, v); vmx = fmaxf(vmx, v);
    }
    __shared__ float smn[256], smx[256];
    smn[t] = vmn; smx[t] = vmx;
    __syncthreads();
    if (t < 64) {
        float m0 = fminf(fminf(smn[t], smn[t + 64]), fminf(smn[t + 128], smn[t + 192]));
        float m1 = fmaxf(fmaxf(smx[t], smx[t + 64]), fmaxf(smx[t + 128], smx[t + 192]));
        pmn[b * 64 + t] = m0; pmx[b * 64 + t] = m1;
    }
}

__global__ __launch_bounds__(256) void k_minmax2(
    const float* __restrict__ pmn, const float* __restrict__ pmx,
    float* __restrict__ mn, float* __restrict__ mx)
{
    const int t = threadIdx.x, col = t & 63, chunk = t >> 6;
    float vmn = FLT_MAX, vmx = -FLT_MAX;
    for (int r = chunk * 16; r < chunk * 16 + 16; ++r) {
        vmn = fminf(vmn, pmn[r * 64 + col]);
        vmx = fmaxf(vmx, pmx[r * 64 + col]);
    }
    __shared__ float smn[256], smx[256];
    smn[t] = vmn; smx[t] = vmx;
    __syncthreads();
    if (t < 64) {
        mn[t] = fminf(fminf(smn[t], smn[t + 64]), fminf(smn[t + 128], smn[t + 192]));
        mx[t] = fmaxf(fmaxf(smx[t], smx[t + 64]), fmaxf(smx[t + 128], smx[t + 192]));
    }
}

// ---------------------------------------------------------------------------
// Kernel 4: per-row head + HPM MLP fwd + closed-form VJP. 1 wave per row.
// ---------------------------------------------------------------------------
__global__ __launch_bounds__(256) void k_finalize(
    const float* __restrict__ h1h, const float* __restrict__ oldh,
    const float* __restrict__ x,
    const float* __restrict__ Wlin, const float* __restrict__ blin,
    const float* __restrict__ Wh1,  const float* __restrict__ bh1,
    const float* __restrict__ Wh2,  const float* __restrict__ bh2,
    const float* __restrict__ mn,   const float* __restrict__ mx,
    float* __restrict__ dout)
{
    float* out_o = dout;                          // [SEQ][10]
    float* out_F = dout + SEQ * OUTW;             // [SEQ][180]
    float* out_A = dout + SEQ * (OUTW + INW);     // [SEQ][318]

    const int wave = threadIdx.x >> 6, lane = threadIdx.x & 63;
    const int row  = blockIdx.x * 4 + wave;

    __shared__ float Xs[4][XW + 2];
    __shared__ float h1sh[4][HID];

    h1sh[wave][lane] = h1h[row * HID + lane];
    float mnv = mn[lane], mxv = mx[lane];
    Xs[wave][254 + lane] = (oldh[row * HID + lane] - mnv) * frcp(mxv - mnv + 1e-6f);
    Xs[wave][10 + lane]  = 0.0f;
    for (int c = lane; c < INW; c += 64) Xs[wave][74 + c] = x[row * INW + c];
    __syncthreads();

    if (lane < OUTW) {
        float o = blin[lane];
#pragma unroll
        for (int k = 0; k < HID; ++k) o += Wlin[lane * HID + k] * h1sh[wave][k];
        Xs[wave][lane] = o;
        out_o[row * OUTW + lane] = o;
    }
    __syncthreads();

    float z0 = 0.f, z1 = 0.f, s0 = 0.f, s1 = 0.f;
    for (int c = lane; c < XW; c += 64) {
        float xv = Xs[wave][c];
        z0 += xv * Wh1[c];
        z1 += xv * Wh1[XW + c];
    }
    for (int j = lane; j < INW; j += 64) {
        s0 += Wh2[j * 2 + 0];
        s1 += Wh2[j * 2 + 1];
    }
#pragma unroll
    for (int off = 32; off; off >>= 1) {
        z0 += __shfl_xor(z0, off); z1 += __shfl_xor(z1, off);
        s0 += __shfl_xor(s0, off); s1 += __shfl_xor(s1, off);
    }
    const float t0 = tanhf_f(z0 + bh1[0]);
    const float t1 = tanhf_f(z1 + bh1[1]);
    const float a0 = -s0 * (1.0f - t0 * t0);
    const float a1 = -s1 * (1.0f - t1 * t1);

    for (int c = lane; c < INW; c += 64)
        out_F[row * INW + c] = -(t0 * Wh2[c * 2 + 0] + t1 * Wh2[c * 2 + 1] + bh2[c]);
    for (int c = lane; c < XW; c += 64)
        out_A[row * XW + c] = a0 * Wh1[c] + a1 * Wh1[XW + c];
}

// ---------------------------------------------------------------------------
extern "C" void kernel_launch(void* const* d_in, const int* in_sizes, int n_in,
                              void* d_out, int out_size, void* d_ws, size_t ws_size,
                              hipStream_t stream)
{
    const float* input = (const float*)d_in[0];
    const float* Wih0  = (const float*)d_in[1];
    const float* Whh0  = (const float*)d_in[2];
    const float* bih0  = (const float*)d_in[3];
    const float* bhh0  = (const float*)d_in[4];
    const float* Wih1  = (const float*)d_in[5];
    const float* Whh1  = (const float*)d_in[6];
    const float* bih1  = (const float*)d_in[7];
    const float* bhh1  = (const float*)d_in[8];
    const float* Wlin  = (const float*)d_in[9];
    const float* blin  = (const float*)d_in[10];
    const float* Wh1   = (const float*)d_in[11];
    const float* bh1   = (const float*)d_in[12];
    const float* Wh2   = (const float*)d_in[13];
    const float* bh2   = (const float*)d_in[14];

    float* ws   = (float*)d_ws;
    float* pre  = ws;                         // SEQ*G4
    float* oldh = pre  + SEQ * G4;            // SEQ*HID
    float* h1h  = oldh + SEQ * HID;           // SEQ*HID
    float* pmn  = h1h  + SEQ * HID;           // 64*64
    float* pmx  = pmn  + 64 * 64;             // 64*64
    float* mn   = pmx  + 64 * 64;             // 64
    float* mx   = mn   + 64;                  // 64
    float* out  = (float*)d_out;

    hipLaunchKernelGGL(k_precompute, dim3(SEQ / PRE_TS), dim3(256), 0, stream,
                       input, Wih0, bih0, bhh0, pre);
    hipLaunchKernelGGL(k_lstm_seq, dim3(1), dim3(768), 0, stream,
                       pre, Whh0, Wih1, Whh1, bih1, bhh1, oldh, h1h);
    hipLaunchKernelGGL(k_minmax1, dim3(64), dim3(256), 0, stream, oldh, pmn, pmx);
    hipLaunchKernelGGL(k_minmax2, dim3(1), dim3(256), 0, stream, pmn, pmx, mn, mx);
    hipLaunchKernelGGL(k_finalize, dim3(SEQ / 4), dim3(256), 0, stream,
                       h1h, oldh, input, Wlin, blin, Wh1, bh1, Wh2, bh2, mn, mx, out);
}

// Round 7
// 6824.910 us; speedup vs baseline: 1.0509x; 1.0273x over previous
//
#include <hip/hip_runtime.h>
#include <hip/hip_bf16.h>
#include <float.h>

#define SEQ   8192
#define INW   180
#define HID   64
#define G4    256   // 4*HID
#define OUTW  10
#define XW    318   // 10 + 64 + 180 + 64

typedef float f32x4 __attribute__((ext_vector_type(4)));

__device__ __forceinline__ float frcp(float x)   { return __builtin_amdgcn_rcpf(x); }
__device__ __forceinline__ float tanhf_f(float x){ return 1.0f - 2.0f * frcp(1.0f + __expf(2.0f * x)); }
// unified gate activation: sigmoid for i/f/o, tanh (=2*sig(2x)-1) for g
__device__ __forceinline__ float gate_act(float x, bool isg) {
    float xx = isg ? 2.0f * x : x;
    float s  = frcp(1.0f + __expf(-xx));
    return isg ? 2.0f * s - 1.0f : s;
}

// DPP quad_perm broadcast — pure VALU
template<int CTRL>
__device__ __forceinline__ float dpp_bcast(float x) {
    return __int_as_float(__builtin_amdgcn_update_dpp(
        0, __float_as_int(x), CTRL, 0xF, 0xF, true));
}

// Opaque 16B load: result of asm volatile cannot be rematerialized, so the
// compiler must keep it VGPR-resident across the loop (the "memory"-clobber
// barriers otherwise force a conservative reload every step — R4-R6 bug).
__device__ __forceinline__ f32x4 opaque_load4(const float* p) {
    f32x4 v;
    asm volatile("global_load_dwordx4 %0, %1, off" : "=v"(v) : "v"(p));
    return v;
}

// ---------------------------------------------------------------------------
// Kernel 1: pre[s][t] = x[s] @ Wih0[row(t)].T + bih0[row(t)] + bhh0[row(t)]
// row(t) = (t&3)*64 + (t>>2)  — unit-major permutation used by k_lstm_seq
// ---------------------------------------------------------------------------
#define PRE_TS 16
__global__ __launch_bounds__(256) void k_precompute(
    const float* __restrict__ x,      // [SEQ][INW]
    const float* __restrict__ Wih0,   // [G4][INW]
    const float* __restrict__ bih0,
    const float* __restrict__ bhh0,
    float* __restrict__ pre)          // [SEQ][G4] (permuted rows)
{
    __shared__ float xT[INW][PRE_TS];
    const int t  = threadIdx.x;
    const int rr = (t & 3) * 64 + (t >> 2);
    const int s0 = blockIdx.x * PRE_TS;
    for (int i = t; i < PRE_TS * INW; i += 256) {
        int s = i / INW, k = i % INW;
        xT[k][s] = x[s0 * INW + i];
    }
    __syncthreads();
    float acc[PRE_TS];
    const float b = bih0[rr] + bhh0[rr];
#pragma unroll
    for (int s = 0; s < PRE_TS; ++s) acc[s] = b;
    for (int k = 0; k < INW; ++k) {
        float w = Wih0[rr * INW + k];
#pragma unroll
        for (int s = 0; s < PRE_TS; ++s) acc[s] += w * xT[k][s];
    }
#pragma unroll
    for (int s = 0; s < PRE_TS; ++s) pre[(s0 + s) * G4 + t] = acc[s];
}

// ---------------------------------------------------------------------------
// Kernel 2: serial 2-layer LSTM, wave-specialized layer pipeline.
// ONE block, 768 threads (12 waves, 3/SIMD). SEQ+1 barrier intervals.
//   t <  256:           layer0, intervals 0..SEQ-1:  H0[s+1]=cell(x(s),H0[s],c0)
//   256 <= t < 768:     layer1, intervals 1..SEQ:    Y[s-1]=cell(H0[s],Y[s-2],c1)
//                       lane-pair matrix split (half0=Wih1 vs h0, half1=Whh1
//                       vs h1), pair-sum shfl_xor(1), 8-lane gate combine.
// Weights loaded once via opaque asm loads -> VGPR-resident for all 8192
// steps (no per-step L2 re-stream, which was the ~2000cyc/step floor).
// ---------------------------------------------------------------------------
__global__ __launch_bounds__(768) __attribute__((amdgpu_waves_per_eu(3, 3)))
void k_lstm_seq(
    const float* __restrict__ pre,    // [SEQ][G4] permuted
    const float* __restrict__ Whh0,   // [G4][HID]
    const float* __restrict__ Wih1,   // [G4][HID]
    const float* __restrict__ Whh1,   // [G4][HID]
    const float* __restrict__ bih1,
    const float* __restrict__ bhh1,
    float* __restrict__ oldh,         // [SEQ][HID] (h0 at START of step s)
    float* __restrict__ h1h)          // [SEQ][HID] (h1 after step s)
{
    const int t = threadIdx.x;

    __shared__ f32x4 h0v[2][16];      // h0 broadcast, double-buffered
    __shared__ f32x4 h1v[2][16];      // h1 broadcast, double-buffered
    if (t < 16) {
        f32x4 z = {0.f, 0.f, 0.f, 0.f};
        h0v[0][t] = z; h0v[1][t] = z; h1v[0][t] = z; h1v[1][t] = z;
    }
    if (t < 64) oldh[t] = 0.0f;
    __syncthreads();

    if (t < 256) {
        // ========== layer-0: full row, DPP quad combine ==========
        const int q    = t;
        const int g    = q & 3;       // gate: 0=i 1=f 2=g 3=o
        const int u    = q >> 2;      // unit
        const int r    = g * 64 + u;  // weight row
        const bool isg = (g == 2);

        f32x4 w0[16];
        {
            const float* W0 = Whh0 + r * HID;
#pragma unroll
            for (int j = 0; j < 16; ++j) w0[j] = opaque_load4(W0 + 4 * j);
            asm volatile("s_waitcnt vmcnt(0)" ::: "memory");
        }
        float c0 = 0.f;
        float preval = pre[q];
        for (int s = 0; s <= SEQ; ++s) {
            if (s < SEQ) {
                const int p = s & 1, pn = p ^ 1;
                const int sn = (s + 1 < SEQ) ? (s + 1) : s;
                float prenext = pre[sn * G4 + q];

                float va = preval, vb = 0.f, vc = 0.f, vd = 0.f;
                const f32x4* H = (const f32x4*)&h0v[p][0];
#pragma unroll
                for (int j = 0; j < 16; j += 2) {
                    f32x4 h0 = H[j],   x0 = w0[j];
                    f32x4 h1 = H[j+1], x1 = w0[j+1];
                    va = fmaf(x0.x, h0.x, va); vb = fmaf(x0.y, h0.y, vb);
                    va = fmaf(x0.z, h0.z, va); vb = fmaf(x0.w, h0.w, vb);
                    vc = fmaf(x1.x, h1.x, vc); vd = fmaf(x1.y, h1.y, vd);
                    vc = fmaf(x1.z, h1.z, vc); vd = fmaf(x1.w, h1.w, vd);
                }
                float a  = gate_act((va + vb) + (vc + vd), isg);
                float ai = dpp_bcast<0x00>(a);
                float af = dpp_bcast<0x55>(a);
                float ag = dpp_bcast<0xAA>(a);
                float ao = dpp_bcast<0xFF>(a);
                c0 = fmaf(af, c0, ai * ag);
                float h0n = ao * tanhf_f(c0);
                if (g == 0) ((float*)&h0v[pn][0])[u] = h0n;
                if (g == 1 && s + 1 < SEQ) oldh[(s + 1) * HID + u] = h0n;
                preval = prenext;
            }
            asm volatile("s_waitcnt lgkmcnt(0)" ::: "memory");
            __builtin_amdgcn_s_barrier();
            asm volatile("" ::: "memory");
        }
    } else {
        // ========== layer-1: lane-pair matrix split ==========
        const int i9   = t - 256;     // 0..511
        const int q    = i9 >> 1;     // row 0..255
        const int half = i9 & 1;      // 0: Wih1 vs h0, 1: Whh1 vs h1
        const int g    = q & 3;
        const int u    = q >> 2;
        const int r    = g * 64 + u;
        const int lane = t & 63;
        const bool isg = (g == 2);
        const bool hi4 = (lane & 4) != 0;

        f32x4 w[16];
        {
            const float* Wb = half ? (Whh1 + r * HID) : (Wih1 + r * HID);
#pragma unroll
            for (int j = 0; j < 16; ++j) w[j] = opaque_load4(Wb + 4 * j);
            asm volatile("s_waitcnt vmcnt(0)" ::: "memory");
        }
        const float b1 = bih1[r] + bhh1[r];
        float c1 = 0.f;
        for (int s = 0; s <= SEQ; ++s) {
            if (s >= 1) {
                const int p = s & 1, pn = p ^ 1;

                float va = half ? 0.0f : b1, vb = 0.f, vc = 0.f, vd = 0.f;
                const f32x4* H = half ? (const f32x4*)&h1v[p][0]
                                      : (const f32x4*)&h0v[p][0];
#pragma unroll
                for (int j = 0; j < 16; j += 2) {
                    f32x4 h0 = H[j],   x0 = w[j];
                    f32x4 h1 = H[j+1], x1 = w[j+1];
                    va = fmaf(x0.x, h0.x, va); vb = fmaf(x0.y, h0.y, vb);
                    va = fmaf(x0.z, h0.z, va); vb = fmaf(x0.w, h0.w, vb);
                    vc = fmaf(x1.x, h1.x, vc); vd = fmaf(x1.y, h1.y, vd);
                    vc = fmaf(x1.z, h1.z, vc); vd = fmaf(x1.w, h1.w, vd);
                }
                float ap = (va + vb) + (vc + vd);
                ap += __shfl_xor(ap, 1);                 // pair sum
                float a  = gate_act(ap, isg);
                float p0 = dpp_bcast<0x00>(a), p2 = dpp_bcast<0xAA>(a);
                float s0 = __shfl_xor(p0, 4), s2 = __shfl_xor(p2, 4);
                float i_ = hi4 ? s0 : p0, f_ = hi4 ? s2 : p2;
                float g_ = hi4 ? p0 : s0, o_ = hi4 ? p2 : s2;
                c1 = fmaf(f_, c1, i_ * g_);
                float h1n = o_ * tanhf_f(c1);            // Y[s-1]
                if ((i9 & 7) == 0) ((float*)&h1v[pn][0])[u] = h1n;
                if ((i9 & 7) == 2) h1h[(s - 1) * HID + u] = h1n;
            }
            asm volatile("s_waitcnt lgkmcnt(0)" ::: "memory");
            __builtin_amdgcn_s_barrier();
            asm volatile("" ::: "memory");
        }
    }
}

// ---------------------------------------------------------------------------
// Kernel 3a/3b: column-wise min/max of oldh (64 cols x 8192 rows)
// ---------------------------------------------------------------------------
__global__ __launch_bounds__(256) void k_minmax1(
    const float* __restrict__ oldh, float* __restrict__ pmn, float* __restrict__ pmx)
{
    const int t = threadIdx.x, b = blockIdx.x;
    float vmn = FLT_MAX, vmx = -FLT_MAX;
    for (int i = t; i < 128 * HID; i += 256) {
        float v = oldh[b * 128 * HID + i];
        vmn = fminf(vmn, v); vmx = fmaxf(vmx, v);
    }
    __shared__ float smn[256], smx[256];
    smn[t] = vmn; smx[t] = vmx;
    __syncthreads();
    if (t < 64) {
        float m0 = fminf(fminf(smn[t], smn[t + 64]), fminf(smn[t + 128], smn[t + 192]));
        float m1 = fmaxf(fmaxf(smx[t], smx[t + 64]), fmaxf(smx[t + 128], smx[t + 192]));
        pmn[b * 64 + t] = m0; pmx[b * 64 + t] = m1;
    }
}

__global__ __launch_bounds__(256) void k_minmax2(
    const float* __restrict__ pmn, const float* __restrict__ pmx,
    float* __restrict__ mn, float* __restrict__ mx)
{
    const int t = threadIdx.x, col = t & 63, chunk = t >> 6;
    float vmn = FLT_MAX, vmx = -FLT_MAX;
    for (int r = chunk * 16; r < chunk * 16 + 16; ++r) {
        vmn = fminf(vmn, pmn[r * 64 + col]);
        vmx = fmaxf(vmx, pmx[r * 64 + col]);
    }
    __shared__ float smn[256], smx[256];
    smn[t] = vmn; smx[t] = vmx;
    __syncthreads();
    if (t < 64) {
        mn[t] = fminf(fminf(smn[t], smn[t + 64]), fminf(smn[t + 128], smn[t + 192]));
        mx[t] = fmaxf(fmaxf(smx[t], smx[t + 64]), fmaxf(smx[t + 128], smx[t + 192]));
    }
}

// ---------------------------------------------------------------------------
// Kernel 4: per-row head + HPM MLP fwd + closed-form VJP. 1 wave per row.
// ---------------------------------------------------------------------------
__global__ __launch_bounds__(256) void k_finalize(
    const float* __restrict__ h1h, const float* __restrict__ oldh,
    const float* __restrict__ x,
    const float* __restrict__ Wlin, const float* __restrict__ blin,
    const float* __restrict__ Wh1,  const float* __restrict__ bh1,
    const float* __restrict__ Wh2,  const float* __restrict__ bh2,
    const float* __restrict__ mn,   const float* __restrict__ mx,
    float* __restrict__ dout)
{
    float* out_o = dout;                          // [SEQ][10]
    float* out_F = dout + SEQ * OUTW;             // [SEQ][180]
    float* out_A = dout + SEQ * (OUTW + INW);     // [SEQ][318]

    const int wave = threadIdx.x >> 6, lane = threadIdx.x & 63;
    const int row  = blockIdx.x * 4 + wave;

    __shared__ float Xs[4][XW + 2];
    __shared__ float h1sh[4][HID];

    h1sh[wave][lane] = h1h[row * HID + lane];
    float mnv = mn[lane], mxv = mx[lane];
    Xs[wave][254 + lane] = (oldh[row * HID + lane] - mnv) * frcp(mxv - mnv + 1e-6f);
    Xs[wave][10 + lane]  = 0.0f;
    for (int c = lane; c < INW; c += 64) Xs[wave][74 + c] = x[row * INW + c];
    __syncthreads();

    if (lane < OUTW) {
        float o = blin[lane];
#pragma unroll
        for (int k = 0; k < HID; ++k) o += Wlin[lane * HID + k] * h1sh[wave][k];
        Xs[wave][lane] = o;
        out_o[row * OUTW + lane] = o;
    }
    __syncthreads();

    float z0 = 0.f, z1 = 0.f, s0 = 0.f, s1 = 0.f;
    for (int c = lane; c < XW; c += 64) {
        float xv = Xs[wave][c];
        z0 += xv * Wh1[c];
        z1 += xv * Wh1[XW + c];
    }
    for (int j = lane; j < INW; j += 64) {
        s0 += Wh2[j * 2 + 0];
        s1 += Wh2[j * 2 + 1];
    }
#pragma unroll
    for (int off = 32; off; off >>= 1) {
        z0 += __shfl_xor(z0, off); z1 += __shfl_xor(z1, off);
        s0 += __shfl_xor(s0, off); s1 += __shfl_xor(s1, off);
    }
    const float t0 = tanhf_f(z0 + bh1[0]);
    const float t1 = tanhf_f(z1 + bh1[1]);
    const float a0 = -s0 * (1.0f - t0 * t0);
    const float a1 = -s1 * (1.0f - t1 * t1);

    for (int c = lane; c < INW; c += 64)
        out_F[row * INW + c] = -(t0 * Wh2[c * 2 + 0] + t1 * Wh2[c * 2 + 1] + bh2[c]);
    for (int c = lane; c < XW; c += 64)
        out_A[row * XW + c] = a0 * Wh1[c] + a1 * Wh1[XW + c];
}

// ---------------------------------------------------------------------------
extern "C" void kernel_launch(void* const* d_in, const int* in_sizes, int n_in,
                              void* d_out, int out_size, void* d_ws, size_t ws_size,
                              hipStream_t stream)
{
    const float* input = (const float*)d_in[0];
    const float* Wih0  = (const float*)d_in[1];
    const float* Whh0  = (const float*)d_in[2];
    const float* bih0  = (const float*)d_in[3];
    const float* bhh0  = (const float*)d_in[4];
    const float* Wih1  = (const float*)d_in[5];
    const float* Whh1  = (const float*)d_in[6];
    const float* bih1  = (const float*)d_in[7];
    const float* bhh1  = (const float*)d_in[8];
    const float* Wlin  = (const float*)d_in[9];
    const float* blin  = (const float*)d_in[10];
    const float* Wh1   = (const float*)d_in[11];
    const float* bh1   = (const float*)d_in[12];
    const float* Wh2   = (const float*)d_in[13];
    const float* bh2   = (const float*)d_in[14];

    float* ws   = (float*)d_ws;
    float* pre  = ws;                         // SEQ*G4
    float* oldh = pre  + SEQ * G4;            // SEQ*HID
    float* h1h  = oldh + SEQ * HID;           // SEQ*HID
    float* pmn  = h1h  + SEQ * HID;           // 64*64
    float* pmx  = pmn  + 64 * 64;             // 64*64
    float* mn   = pmx  + 64 * 64;             // 64
    float* mx   = mn   + 64;                  // 64
    float* out  = (float*)d_out;

    hipLaunchKernelGGL(k_precompute, dim3(SEQ / PRE_TS), dim3(256), 0, stream,
                       input, Wih0, bih0, bhh0, pre);
    hipLaunchKernelGGL(k_lstm_seq, dim3(1), dim3(768), 0, stream,
                       pre, Whh0, Wih1, Whh1, bih1, bhh1, oldh, h1h);
    hipLaunchKernelGGL(k_minmax1, dim3(64), dim3(256), 0, stream, oldh, pmn, pmx);
    hipLaunchKernelGGL(k_minmax2, dim3(1), dim3(256), 0, stream, pmn, pmx, mn, mx);
    hipLaunchKernelGGL(k_finalize, dim3(SEQ / 4), dim3(256), 0, stream,
                       h1h, oldh, input, Wlin, blin, Wh1, bh1, Wh2, bh2, mn, mx, out);
}

// Round 8
// 4918.799 us; speedup vs baseline: 1.4581x; 1.3875x over previous
//
#include <hip/hip_runtime.h>
#include <hip/hip_bf16.h>
#include <float.h>

#define SEQ   8192
#define INW   180
#define HID   64
#define G4    256   // 4*HID
#define OUTW  10
#define XW    318   // 10 + 64 + 180 + 64

typedef float f32x4 __attribute__((ext_vector_type(4)));
typedef _Float16 h16x2 __attribute__((ext_vector_type(2)));
typedef unsigned int uint32;

__device__ __forceinline__ float frcp(float x)   { return __builtin_amdgcn_rcpf(x); }
__device__ __forceinline__ float tanhf_f(float x){ return 1.0f - 2.0f * frcp(1.0f + __expf(2.0f * x)); }
__device__ __forceinline__ float gate_act(float x, bool isg) {
    float xx = isg ? 2.0f * x : x;
    float s  = frcp(1.0f + __expf(-xx));
    return isg ? 2.0f * s - 1.0f : s;
}

template<int CTRL>
__device__ __forceinline__ float dpp_bcast(float x) {
    return __int_as_float(__builtin_amdgcn_update_dpp(
        0, __float_as_int(x), CTRL, 0xF, 0xF, true));
}

// v_dot2_f32_f16: acc += a.x*b.x + a.y*b.y  (f32 accumulate, exact products)
__device__ __forceinline__ float fdot2h(h16x2 a, h16x2 b, float c) {
#if __has_builtin(__builtin_amdgcn_fdot2)
    return __builtin_amdgcn_fdot2(a, b, c, false);
#else
    asm("v_dot2_f32_f16 %0, %1, %2, %3" : "=v"(c) : "v"(a), "v"(b), "0"(c));
    return c;
#endif
}

__device__ __forceinline__ h16x2 h2f(float f)   { return __builtin_bit_cast(h16x2, f); }
__device__ __forceinline__ h16x2 h2u(uint32 u)  { return __builtin_bit_cast(h16x2, u); }
__device__ __forceinline__ uint32 pack_h2(float lo, float hi) {
    h16x2 h; h.x = (_Float16)lo; h.y = (_Float16)hi;
    return __builtin_bit_cast(uint32, h);
}

// Opaque 16B load: asm volatile result can't be rematerialized -> the 8 weight
// quads (32 VGPR) stay register-resident across all 8192 steps.
__device__ __forceinline__ f32x4 opaque_load4(const float* p) {
    f32x4 v;
    asm volatile("global_load_dwordx4 %0, %1, off" : "=v"(v) : "v"(p));
    return v;
}

// ---------------------------------------------------------------------------
// Kernel 0: pack the 3 recurrent matrices to half2 (pairs along K).
// dst[mat][r*32 + k2] = (f16(W[r][2k2]), f16(W[r][2k2+1]))
// ---------------------------------------------------------------------------
__global__ __launch_bounds__(256) void k_packw(
    const float* __restrict__ Whh0, const float* __restrict__ Wih1,
    const float* __restrict__ Whh1,
    uint32* __restrict__ w0h, uint32* __restrict__ w1ah, uint32* __restrict__ w1bh)
{
    const int gid = blockIdx.x * 256 + threadIdx.x;   // 0 .. 3*8192-1
    const int mat = gid >> 13;
    const int i   = gid & 8191;
    const int r   = i >> 5, k2 = i & 31;
    const float* S = (mat == 0) ? Whh0 : (mat == 1) ? Wih1 : Whh1;
    uint32*      D = (mat == 0) ? w0h  : (mat == 1) ? w1ah : w1bh;
    D[i] = pack_h2(S[r * 64 + 2 * k2], S[r * 64 + 2 * k2 + 1]);
}

// ---------------------------------------------------------------------------
// Kernel 1: pre[s][t] = x[s] @ Wih0[row(t)].T + bih0[row(t)] + bhh0[row(t)]
// row(t) = (t&3)*64 + (t>>2)  (f32, unchanged)
// ---------------------------------------------------------------------------
#define PRE_TS 16
__global__ __launch_bounds__(256) void k_precompute(
    const float* __restrict__ x, const float* __restrict__ Wih0,
    const float* __restrict__ bih0, const float* __restrict__ bhh0,
    float* __restrict__ pre)
{
    __shared__ float xT[INW][PRE_TS];
    const int t  = threadIdx.x;
    const int rr = (t & 3) * 64 + (t >> 2);
    const int s0 = blockIdx.x * PRE_TS;
    for (int i = t; i < PRE_TS * INW; i += 256) {
        int s = i / INW, k = i % INW;
        xT[k][s] = x[s0 * INW + i];
    }
    __syncthreads();
    float acc[PRE_TS];
    const float b = bih0[rr] + bhh0[rr];
#pragma unroll
    for (int s = 0; s < PRE_TS; ++s) acc[s] = b;
    for (int k = 0; k < INW; ++k) {
        float w = Wih0[rr * INW + k];
#pragma unroll
        for (int s = 0; s < PRE_TS; ++s) acc[s] += w * xT[k][s];
    }
#pragma unroll
    for (int s = 0; s < PRE_TS; ++s) pre[(s0 + s) * G4 + t] = acc[s];
}

// 4-accumulator dot over one 16B weight quad (4 half2 = 8 elems)
#define DOT4(A0, A1, A2, A3, WQ, HQ)                         \
    A0 = fdot2h(h2f((WQ).x), h2u((HQ).x), A0);               \
    A1 = fdot2h(h2f((WQ).y), h2u((HQ).y), A1);               \
    A2 = fdot2h(h2f((WQ).z), h2u((HQ).z), A2);               \
    A3 = fdot2h(h2f((WQ).w), h2u((HQ).w), A3);

// ---------------------------------------------------------------------------
// Kernel 2: serial 2-layer LSTM, wave-specialized, fp16-dot2 recurrence.
// ONE block, 768 threads (12 waves). SEQ+1 barrier intervals (R4-verified skew):
//   t <  256 (q=t):     layer0, s=0..SEQ-1: H0[s+1]=cell(x(s),H0[s],c0)
//                       full Whh0 row (8 fp16-quads), DPP quad gate-combine.
//   t >= 256 (i9=t-256): layer1, s=1..SEQ:  Y[s-1]=cell(H0[s],Y[s-2],c1)
//                       half0=Wih1 row vs h0, half1=Whh1 row vs h1;
//                       pair-sum shfl_xor(1), 8-lane gate combine.
// h exchanged through LDS as packed half2 (32 dwords per vector).
// Weights: 8 opaque 16B loads/thread = 32 VGPR -> fits under the ~68-VGPR
// allocator cap (the f32 version's 64 VGPR did not; it spilled to scratch
// and re-streamed 192KB/step = the 2000cyc/step floor of R4-R7).
// ---------------------------------------------------------------------------
__global__ __launch_bounds__(768) __attribute__((amdgpu_waves_per_eu(3, 3)))
void k_lstm_seq(
    const float* __restrict__ pre,
    const uint32* __restrict__ w0h,    // [G4][32] packed Whh0
    const uint32* __restrict__ w1ah,   // [G4][32] packed Wih1
    const uint32* __restrict__ w1bh,   // [G4][32] packed Whh1
    const float* __restrict__ bih1, const float* __restrict__ bhh1,
    float* __restrict__ oldh, float* __restrict__ h1h)
{
    const int t = threadIdx.x;

    __shared__ __attribute__((aligned(16))) uint32 h0p[2][32];
    __shared__ __attribute__((aligned(16))) uint32 h1p[2][32];
    if (t < 32) { h0p[0][t] = 0u; h0p[1][t] = 0u; h1p[0][t] = 0u; h1p[1][t] = 0u; }
    if (t < 64) oldh[t] = 0.0f;
    __syncthreads();

    if (t < 256) {
        // ================= layer-0 =================
        const int q = t, g = q & 3, u = q >> 2, r = g * 64 + u;
        const bool isg = (g == 2);

        f32x4 w[8];
        {
            const float* W = (const float*)(w0h + r * 32);
#pragma unroll
            for (int j = 0; j < 8; ++j) w[j] = opaque_load4(W + 4 * j);
            asm volatile("s_waitcnt vmcnt(0)" ::: "memory");
        }
        float c0 = 0.f;
        float preval = pre[q];
        for (int s = 0; s <= SEQ; ++s) {
            if (s < SEQ) {
                const int p = s & 1, pn = p ^ 1;
                const int sn = (s + 1 < SEQ) ? (s + 1) : s;
                float prenext = pre[sn * G4 + q];

                const uint4* Hp = (const uint4*)&h0p[p][0];
                float a0 = preval, a1 = 0.f, a2 = 0.f, a3 = 0.f;
                {
                    uint4 hq0 = Hp[0], hq1 = Hp[1], hq2 = Hp[2], hq3 = Hp[3];
                    DOT4(a0, a1, a2, a3, w[0], hq0)
                    DOT4(a0, a1, a2, a3, w[1], hq1)
                    DOT4(a0, a1, a2, a3, w[2], hq2)
                    DOT4(a0, a1, a2, a3, w[3], hq3)
                }
                __builtin_amdgcn_sched_barrier(0);
                {
                    uint4 hq4 = Hp[4], hq5 = Hp[5], hq6 = Hp[6], hq7 = Hp[7];
                    DOT4(a0, a1, a2, a3, w[4], hq4)
                    DOT4(a0, a1, a2, a3, w[5], hq5)
                    DOT4(a0, a1, a2, a3, w[6], hq6)
                    DOT4(a0, a1, a2, a3, w[7], hq7)
                }
                float a  = gate_act((a0 + a1) + (a2 + a3), isg);
                float ai = dpp_bcast<0x00>(a);
                float af = dpp_bcast<0x55>(a);
                float ag = dpp_bcast<0xAA>(a);
                float ao = dpp_bcast<0xFF>(a);
                c0 = fmaf(af, c0, ai * ag);
                float h0n = ao * tanhf_f(c0);
                float hpart = __shfl_xor(h0n, 4);        // partner unit's h
                if ((q & 7) == 0) h0p[pn][u >> 1] = pack_h2(h0n, hpart);
                if ((q & 3) == 1 && s + 1 < SEQ) oldh[(s + 1) * HID + u] = h0n;
                preval = prenext;
            }
            asm volatile("s_waitcnt lgkmcnt(0)" ::: "memory");
            __builtin_amdgcn_s_barrier();
            asm volatile("" ::: "memory");
        }
    } else {
        // ================= layer-1 =================
        const int i9   = t - 256;       // 0..511
        const int q    = i9 >> 1;       // row 0..255
        const int half = i9 & 1;        // 0: Wih1 vs h0, 1: Whh1 vs h1
        const int g    = q & 3, u = q >> 2, r = g * 64 + u;
        const int lane = t & 63;
        const bool isg = (g == 2);
        const bool hi4 = (lane & 4) != 0;

        f32x4 w[8];
        {
            const uint32* Wb = half ? (w1bh + r * 32) : (w1ah + r * 32);
            const float* W = (const float*)Wb;
#pragma unroll
            for (int j = 0; j < 8; ++j) w[j] = opaque_load4(W + 4 * j);
            asm volatile("s_waitcnt vmcnt(0)" ::: "memory");
        }
        const float b1 = bih1[r] + bhh1[r];
        float c1 = 0.f;
        for (int s = 0; s <= SEQ; ++s) {
            if (s >= 1) {
                const int p = s & 1, pn = p ^ 1;

                const uint4* Hp = half ? (const uint4*)&h1p[p][0]
                                       : (const uint4*)&h0p[p][0];
                float a0 = half ? 0.f : b1, a1 = 0.f, a2 = 0.f, a3 = 0.f;
                {
                    uint4 hq0 = Hp[0], hq1 = Hp[1], hq2 = Hp[2], hq3 = Hp[3];
                    DOT4(a0, a1, a2, a3, w[0], hq0)
                    DOT4(a0, a1, a2, a3, w[1], hq1)
                    DOT4(a0, a1, a2, a3, w[2], hq2)
                    DOT4(a0, a1, a2, a3, w[3], hq3)
                }
                __builtin_amdgcn_sched_barrier(0);
                {
                    uint4 hq4 = Hp[4], hq5 = Hp[5], hq6 = Hp[6], hq7 = Hp[7];
                    DOT4(a0, a1, a2, a3, w[4], hq4)
                    DOT4(a0, a1, a2, a3, w[5], hq5)
                    DOT4(a0, a1, a2, a3, w[6], hq6)
                    DOT4(a0, a1, a2, a3, w[7], hq7)
                }
                float ap = (a0 + a1) + (a2 + a3);
                ap += __shfl_xor(ap, 1);                 // pair sum
                float a  = gate_act(ap, isg);
                float p0 = dpp_bcast<0x00>(a), p2 = dpp_bcast<0xAA>(a);
                float s0 = __shfl_xor(p0, 4), s2 = __shfl_xor(p2, 4);
                float i_ = hi4 ? s0 : p0, f_ = hi4 ? s2 : p2;
                float g_ = hi4 ? p0 : s0, o_ = hi4 ? p2 : s2;
                c1 = fmaf(f_, c1, i_ * g_);
                float h1n = o_ * tanhf_f(c1);            // Y[s-1]
                float hpart = __shfl_xor(h1n, 8);        // partner unit's h
                if ((i9 & 15) == 0) h1p[pn][u >> 1] = pack_h2(h1n, hpart);
                if ((i9 & 7) == 2) h1h[(s - 1) * HID + u] = h1n;
            }
            asm volatile("s_waitcnt lgkmcnt(0)" ::: "memory");
            __builtin_amdgcn_s_barrier();
            asm volatile("" ::: "memory");
        }
    }
}

// ---------------------------------------------------------------------------
// Kernel 3a/3b: column-wise min/max of oldh (64 cols x 8192 rows)
// ---------------------------------------------------------------------------
__global__ __launch_bounds__(256) void k_minmax1(
    const float* __restrict__ oldh, float* __restrict__ pmn, float* __restrict__ pmx)
{
    const int t = threadIdx.x, b = blockIdx.x;
    float vmn = FLT_MAX, vmx = -FLT_MAX;
    for (int i = t; i < 128 * HID; i += 256) {
        float v = oldh[b * 128 * HID + i];
        vmn = fminf(vmn, v); vmx = fmaxf(vmx, v);
    }
    __shared__ float smn[256], smx[256];
    smn[t] = vmn; smx[t] = vmx;
    __syncthreads();
    if (t < 64) {
        float m0 = fminf(fminf(smn[t], smn[t + 64]), fminf(smn[t + 128], smn[t + 192]));
        float m1 = fmaxf(fmaxf(smx[t], smx[t + 64]), fmaxf(smx[t + 128], smx[t + 192]));
        pmn[b * 64 + t] = m0; pmx[b * 64 + t] = m1;
    }
}

__global__ __launch_bounds__(256) void k_minmax2(
    const float* __restrict__ pmn, const float* __restrict__ pmx,
    float* __restrict__ mn, float* __restrict__ mx)
{
    const int t = threadIdx.x, col = t & 63, chunk = t >> 6;
    float vmn = FLT_MAX, vmx = -FLT_MAX;
    for (int r = chunk * 16; r < chunk * 16 + 16; ++r) {
        vmn = fminf(vmn, pmn[r * 64 + col]);
        vmx = fmaxf(vmx, pmx[r * 64 + col]);
    }
    __shared__ float smn[256], smx[256];
    smn[t] = vmn; smx[t] = vmx;
    __syncthreads();
    if (t < 64) {
        mn[t] = fminf(fminf(smn[t], smn[t + 64]), fminf(smn[t + 128], smn[t + 192]));
        mx[t] = fmaxf(fmaxf(smx[t], smx[t + 64]), fmaxf(smx[t + 128], smx[t + 192]));
    }
}

// ---------------------------------------------------------------------------
// Kernel 4: per-row head + HPM MLP fwd + closed-form VJP. 1 wave per row.
// ---------------------------------------------------------------------------
__global__ __launch_bounds__(256) void k_finalize(
    const float* __restrict__ h1h, const float* __restrict__ oldh,
    const float* __restrict__ x,
    const float* __restrict__ Wlin, const float* __restrict__ blin,
    const float* __restrict__ Wh1,  const float* __restrict__ bh1,
    const float* __restrict__ Wh2,  const float* __restrict__ bh2,
    const float* __restrict__ mn,   const float* __restrict__ mx,
    float* __restrict__ dout)
{
    float* out_o = dout;                          // [SEQ][10]
    float* out_F = dout + SEQ * OUTW;             // [SEQ][180]
    float* out_A = dout + SEQ * (OUTW + INW);     // [SEQ][318]

    const int wave = threadIdx.x >> 6, lane = threadIdx.x & 63;
    const int row  = blockIdx.x * 4 + wave;

    __shared__ float Xs[4][XW + 2];
    __shared__ float h1sh[4][HID];

    h1sh[wave][lane] = h1h[row * HID + lane];
    float mnv = mn[lane], mxv = mx[lane];
    Xs[wave][254 + lane] = (oldh[row * HID + lane] - mnv) * frcp(mxv - mnv + 1e-6f);
    Xs[wave][10 + lane]  = 0.0f;
    for (int c = lane; c < INW; c += 64) Xs[wave][74 + c] = x[row * INW + c];
    __syncthreads();

    if (lane < OUTW) {
        float o = blin[lane];
#pragma unroll
        for (int k = 0; k < HID; ++k) o += Wlin[lane * HID + k] * h1sh[wave][k];
        Xs[wave][lane] = o;
        out_o[row * OUTW + lane] = o;
    }
    __syncthreads();

    float z0 = 0.f, z1 = 0.f, s0 = 0.f, s1 = 0.f;
    for (int c = lane; c < XW; c += 64) {
        float xv = Xs[wave][c];
        z0 += xv * Wh1[c];
        z1 += xv * Wh1[XW + c];
    }
    for (int j = lane; j < INW; j += 64) {
        s0 += Wh2[j * 2 + 0];
        s1 += Wh2[j * 2 + 1];
    }
#pragma unroll
    for (int off = 32; off; off >>= 1) {
        z0 += __shfl_xor(z0, off); z1 += __shfl_xor(z1, off);
        s0 += __shfl_xor(s0, off); s1 += __shfl_xor(s1, off);
    }
    const float t0 = tanhf_f(z0 + bh1[0]);
    const float t1 = tanhf_f(z1 + bh1[1]);
    const float a0 = -s0 * (1.0f - t0 * t0);
    const float a1 = -s1 * (1.0f - t1 * t1);

    for (int c = lane; c < INW; c += 64)
        out_F[row * INW + c] = -(t0 * Wh2[c * 2 + 0] + t1 * Wh2[c * 2 + 1] + bh2[c]);
    for (int c = lane; c < XW; c += 64)
        out_A[row * XW + c] = a0 * Wh1[c] + a1 * Wh1[XW + c];
}

// ---------------------------------------------------------------------------
extern "C" void kernel_launch(void* const* d_in, const int* in_sizes, int n_in,
                              void* d_out, int out_size, void* d_ws, size_t ws_size,
                              hipStream_t stream)
{
    const float* input = (const float*)d_in[0];
    const float* Wih0  = (const float*)d_in[1];
    const float* Whh0  = (const float*)d_in[2];
    const float* bih0  = (const float*)d_in[3];
    const float* bhh0  = (const float*)d_in[4];
    const float* Wih1  = (const float*)d_in[5];
    const float* Whh1  = (const float*)d_in[6];
    const float* bih1  = (const float*)d_in[7];
    const float* bhh1  = (const float*)d_in[8];
    const float* Wlin  = (const float*)d_in[9];
    const float* blin  = (const float*)d_in[10];
    const float* Wh1   = (const float*)d_in[11];
    const float* bh1   = (const float*)d_in[12];
    const float* Wh2   = (const float*)d_in[13];
    const float* bh2   = (const float*)d_in[14];

    float* ws   = (float*)d_ws;
    float* pre  = ws;                         // SEQ*G4
    float* oldh = pre  + SEQ * G4;            // SEQ*HID
    float* h1h  = oldh + SEQ * HID;           // SEQ*HID
    float* pmn  = h1h  + SEQ * HID;           // 64*64
    float* pmx  = pmn  + 64 * 64;             // 64*64
    float* mn   = pmx  + 64 * 64;             // 64
    float* mx   = mn   + 64;                  // 64
    uint32* w0h  = (uint32*)(mx + 64);        // G4*32 packed half2
    uint32* w1ah = w0h  + G4 * 32;
    uint32* w1bh = w1ah + G4 * 32;
    float* out  = (float*)d_out;

    hipLaunchKernelGGL(k_packw, dim3(96), dim3(256), 0, stream,
                       Whh0, Wih1, Whh1, w0h, w1ah, w1bh);
    hipLaunchKernelGGL(k_precompute, dim3(SEQ / PRE_TS), dim3(256), 0, stream,
                       input, Wih0, bih0, bhh0, pre);
    hipLaunchKernelGGL(k_lstm_seq, dim3(1), dim3(768), 0, stream,
                       pre, w0h, w1ah, w1bh, bih1, bhh1, oldh, h1h);
    hipLaunchKernelGGL(k_minmax1, dim3(64), dim3(256), 0, stream, oldh, pmn, pmx);
    hipLaunchKernelGGL(k_minmax2, dim3(1), dim3(256), 0, stream, pmn, pmx, mn, mx);
    hipLaunchKernelGGL(k_finalize, dim3(SEQ / 4), dim3(256), 0, stream,
                       h1h, oldh, input, Wlin, blin, Wh1, bh1, Wh2, bh2, mn, mx, out);
}

// Round 9
// 4313.291 us; speedup vs baseline: 1.6628x; 1.1404x over previous
//
#include <hip/hip_runtime.h>
#include <hip/hip_bf16.h>
#include <float.h>

#define SEQ   8192
#define INW   180
#define HID   64
#define G4    256   // 4*HID
#define OUTW  10
#define XW    318   // 10 + 64 + 180 + 64

typedef float f32x4 __attribute__((ext_vector_type(4)));
typedef _Float16 h16x2 __attribute__((ext_vector_type(2)));
typedef unsigned int uint32;

__device__ __forceinline__ float frcp(float x)   { return __builtin_amdgcn_rcpf(x); }
__device__ __forceinline__ float tanhf_f(float x){ return 1.0f - 2.0f * frcp(1.0f + __expf(2.0f * x)); }
__device__ __forceinline__ float gate_act(float x, bool isg) {
    float xx = isg ? 2.0f * x : x;
    float s  = frcp(1.0f + __expf(-xx));
    return isg ? 2.0f * s - 1.0f : s;
}

template<int CTRL>
__device__ __forceinline__ float dpp_bcast(float x) {
    return __int_as_float(__builtin_amdgcn_update_dpp(
        0, __float_as_int(x), CTRL, 0xF, 0xF, true));
}

// v_dot2_f32_f16: acc += a.x*b.x + a.y*b.y  (f32 accumulate, exact products)
__device__ __forceinline__ float fdot2h(h16x2 a, h16x2 b, float c) {
#if __has_builtin(__builtin_amdgcn_fdot2)
    return __builtin_amdgcn_fdot2(a, b, c, false);
#else
    asm("v_dot2_f32_f16 %0, %1, %2, %3" : "=v"(c) : "v"(a), "v"(b), "0"(c));
    return c;
#endif
}

__device__ __forceinline__ h16x2 h2f(float f)   { return __builtin_bit_cast(h16x2, f); }
__device__ __forceinline__ h16x2 h2u(uint32 u)  { return __builtin_bit_cast(h16x2, u); }
__device__ __forceinline__ uint32 pack_h2(float lo, float hi) {
    h16x2 h; h.x = (_Float16)lo; h.y = (_Float16)hi;
    return __builtin_bit_cast(uint32, h);
}

// Opaque 16B load: asm volatile result can't be rematerialized -> weight
// quads stay VGPR-resident (barriers with "memory" clobber otherwise let the
// compiler legally re-load them every step — the R4-R7 2000cyc/step floor).
__device__ __forceinline__ f32x4 opaque_load4(const float* p) {
    f32x4 v;
    asm volatile("global_load_dwordx4 %0, %1, off" : "=v"(v) : "v"(p));
    return v;
}

// ---------------------------------------------------------------------------
// Kernel 0: pack the 3 recurrent matrices to half2 (pairs along K).
// ---------------------------------------------------------------------------
__global__ __launch_bounds__(256) void k_packw(
    const float* __restrict__ Whh0, const float* __restrict__ Wih1,
    const float* __restrict__ Whh1,
    uint32* __restrict__ w0h, uint32* __restrict__ w1ah, uint32* __restrict__ w1bh)
{
    const int gid = blockIdx.x * 256 + threadIdx.x;   // 0 .. 3*8192-1
    const int mat = gid >> 13;
    const int i   = gid & 8191;
    const int r   = i >> 5, k2 = i & 31;
    const float* S = (mat == 0) ? Whh0 : (mat == 1) ? Wih1 : Whh1;
    uint32*      D = (mat == 0) ? w0h  : (mat == 1) ? w1ah : w1bh;
    D[i] = pack_h2(S[r * 64 + 2 * k2], S[r * 64 + 2 * k2 + 1]);
}

// ---------------------------------------------------------------------------
// Kernel 1: pre[s][t] = x[s] @ Wih0[row(t)].T + bih0[row(t)] + bhh0[row(t)]
// row(t) = (t&3)*64 + (t>>2)  (f32, unchanged)
// ---------------------------------------------------------------------------
#define PRE_TS 16
__global__ __launch_bounds__(256) void k_precompute(
    const float* __restrict__ x, const float* __restrict__ Wih0,
    const float* __restrict__ bih0, const float* __restrict__ bhh0,
    float* __restrict__ pre)
{
    __shared__ float xT[INW][PRE_TS];
    const int t  = threadIdx.x;
    const int rr = (t & 3) * 64 + (t >> 2);
    const int s0 = blockIdx.x * PRE_TS;
    for (int i = t; i < PRE_TS * INW; i += 256) {
        int s = i / INW, k = i % INW;
        xT[k][s] = x[s0 * INW + i];
    }
    __syncthreads();
    float acc[PRE_TS];
    const float b = bih0[rr] + bhh0[rr];
#pragma unroll
    for (int s = 0; s < PRE_TS; ++s) acc[s] = b;
    for (int k = 0; k < INW; ++k) {
        float w = Wih0[rr * INW + k];
#pragma unroll
        for (int s = 0; s < PRE_TS; ++s) acc[s] += w * xT[k][s];
    }
#pragma unroll
    for (int s = 0; s < PRE_TS; ++s) pre[(s0 + s) * G4 + t] = acc[s];
}

// 4-accumulator dot over one 16B weight quad (4 half2 = 8 elems)
#define DOT4(A0, A1, A2, A3, WQ, HQ)                         \
    A0 = fdot2h(h2f((WQ).x), h2u((HQ).x), A0);               \
    A1 = fdot2h(h2f((WQ).y), h2u((HQ).y), A1);               \
    A2 = fdot2h(h2f((WQ).z), h2u((HQ).z), A2);               \
    A3 = fdot2h(h2f((WQ).w), h2u((HQ).w), A3);

// ---------------------------------------------------------------------------
// Kernel 2: serial 2-layer LSTM, wave-specialized, fp16-dot2 recurrence.
// ONE block, 512 threads (8 waves, 2/SIMD). SEQ+1 barrier intervals
// (R4-verified skew), one s_barrier per interval:
//   t <  256 (q=t):     layer0, s=0..SEQ-1: H0[s+1]=cell(x(s),H0[s],c0)
//                       full Whh0 row (8 fp16-quads), DPP quad gate-combine.
//   t >= 256 (q=t-256): layer1, s=1..SEQ:  Y[s-1]=cell(H0[s],Y[s-2],c1)
//                       FULL rows of BOTH Wih1 and Whh1 (16 fp16-quads),
//                       same DPP quad gate-combine (no pair-sum).
// amdgpu_num_vgpr(168): explicit VGPR allocation request — the occupancy-
// driven default cap (512thr -> 76) is what forced weight spill in R4-R8.
// ---------------------------------------------------------------------------
__global__ __launch_bounds__(512) __attribute__((amdgpu_num_vgpr(168)))
void k_lstm_seq(
    const float* __restrict__ pre,
    const uint32* __restrict__ w0h,    // [G4][32] packed Whh0
    const uint32* __restrict__ w1ah,   // [G4][32] packed Wih1
    const uint32* __restrict__ w1bh,   // [G4][32] packed Whh1
    const float* __restrict__ bih1, const float* __restrict__ bhh1,
    float* __restrict__ oldh, float* __restrict__ h1h)
{
    const int t = threadIdx.x;

    __shared__ __attribute__((aligned(16))) uint32 h0p[2][32];
    __shared__ __attribute__((aligned(16))) uint32 h1p[2][32];
    if (t < 32) { h0p[0][t] = 0u; h0p[1][t] = 0u; h1p[0][t] = 0u; h1p[1][t] = 0u; }
    if (t < 64) oldh[t] = 0.0f;
    __syncthreads();

    if (t < 256) {
        // ================= layer-0 (identical to R8-verified) =============
        const int q = t, g = q & 3, u = q >> 2, r = g * 64 + u;
        const bool isg = (g == 2);

        f32x4 w[8];
        {
            const float* W = (const float*)(w0h + r * 32);
#pragma unroll
            for (int j = 0; j < 8; ++j) w[j] = opaque_load4(W + 4 * j);
            asm volatile("s_waitcnt vmcnt(0)" ::: "memory");
        }
        float c0 = 0.f;
        float preval = pre[q];
        for (int s = 0; s <= SEQ; ++s) {
            if (s < SEQ) {
                const int p = s & 1, pn = p ^ 1;
                const int sn = (s + 1 < SEQ) ? (s + 1) : s;
                float prenext = pre[sn * G4 + q];

                const uint4* Hp = (const uint4*)&h0p[p][0];
                float a0 = preval, a1 = 0.f, a2 = 0.f, a3 = 0.f;
                {
                    uint4 hq0 = Hp[0], hq1 = Hp[1], hq2 = Hp[2], hq3 = Hp[3];
                    DOT4(a0, a1, a2, a3, w[0], hq0)
                    DOT4(a0, a1, a2, a3, w[1], hq1)
                    DOT4(a0, a1, a2, a3, w[2], hq2)
                    DOT4(a0, a1, a2, a3, w[3], hq3)
                }
                __builtin_amdgcn_sched_barrier(0);
                {
                    uint4 hq4 = Hp[4], hq5 = Hp[5], hq6 = Hp[6], hq7 = Hp[7];
                    DOT4(a0, a1, a2, a3, w[4], hq4)
                    DOT4(a0, a1, a2, a3, w[5], hq5)
                    DOT4(a0, a1, a2, a3, w[6], hq6)
                    DOT4(a0, a1, a2, a3, w[7], hq7)
                }
                float a  = gate_act((a0 + a1) + (a2 + a3), isg);
                float ai = dpp_bcast<0x00>(a);
                float af = dpp_bcast<0x55>(a);
                float ag = dpp_bcast<0xAA>(a);
                float ao = dpp_bcast<0xFF>(a);
                c0 = fmaf(af, c0, ai * ag);
                float h0n = ao * tanhf_f(c0);
                float hpart = __shfl_xor(h0n, 4);        // partner unit u+1
                if ((q & 7) == 0) h0p[pn][u >> 1] = pack_h2(h0n, hpart);
                if ((q & 3) == 1 && s + 1 < SEQ) oldh[(s + 1) * HID + u] = h0n;
                preval = prenext;
            }
            asm volatile("s_waitcnt lgkmcnt(0)" ::: "memory");
            __builtin_amdgcn_s_barrier();
            asm volatile("" ::: "memory");
        }
    } else {
        // ================= layer-1: full rows of BOTH matrices ============
        const int q = t - 256, g = q & 3, u = q >> 2, r = g * 64 + u;
        const bool isg = (g == 2);

        f32x4 wa[8], wb[8];
        {
            const float* Wa = (const float*)(w1ah + r * 32);
            const float* Wb = (const float*)(w1bh + r * 32);
#pragma unroll
            for (int j = 0; j < 8; ++j) wa[j] = opaque_load4(Wa + 4 * j);
#pragma unroll
            for (int j = 0; j < 8; ++j) wb[j] = opaque_load4(Wb + 4 * j);
            asm volatile("s_waitcnt vmcnt(0)" ::: "memory");
        }
        const float b1 = bih1[r] + bhh1[r];
        float c1 = 0.f;
        for (int s = 0; s <= SEQ; ++s) {
            if (s >= 1) {
                const int p = s & 1, pn = p ^ 1;
                const uint4* H0 = (const uint4*)&h0p[p][0];   // H0[s]
                const uint4* H1 = (const uint4*)&h1p[p][0];   // Y[s-2]
                float a0 = b1, a1 = 0.f, a2 = 0.f, a3 = 0.f;
                {
                    uint4 hq0 = H0[0], hq1 = H0[1], hq2 = H0[2], hq3 = H0[3];
                    DOT4(a0, a1, a2, a3, wa[0], hq0)
                    DOT4(a0, a1, a2, a3, wa[1], hq1)
                    DOT4(a0, a1, a2, a3, wa[2], hq2)
                    DOT4(a0, a1, a2, a3, wa[3], hq3)
                }
                __builtin_amdgcn_sched_barrier(0);
                {
                    uint4 hq4 = H0[4], hq5 = H0[5], hq6 = H0[6], hq7 = H0[7];
                    DOT4(a0, a1, a2, a3, wa[4], hq4)
                    DOT4(a0, a1, a2, a3, wa[5], hq5)
                    DOT4(a0, a1, a2, a3, wa[6], hq6)
                    DOT4(a0, a1, a2, a3, wa[7], hq7)
                }
                __builtin_amdgcn_sched_barrier(0);
                {
                    uint4 hq0 = H1[0], hq1 = H1[1], hq2 = H1[2], hq3 = H1[3];
                    DOT4(a0, a1, a2, a3, wb[0], hq0)
                    DOT4(a0, a1, a2, a3, wb[1], hq1)
                    DOT4(a0, a1, a2, a3, wb[2], hq2)
                    DOT4(a0, a1, a2, a3, wb[3], hq3)
                }
                __builtin_amdgcn_sched_barrier(0);
                {
                    uint4 hq4 = H1[4], hq5 = H1[5], hq6 = H1[6], hq7 = H1[7];
                    DOT4(a0, a1, a2, a3, wb[4], hq4)
                    DOT4(a0, a1, a2, a3, wb[5], hq5)
                    DOT4(a0, a1, a2, a3, wb[6], hq6)
                    DOT4(a0, a1, a2, a3, wb[7], hq7)
                }
                float a  = gate_act((a0 + a1) + (a2 + a3), isg);
                float ai = dpp_bcast<0x00>(a);
                float af = dpp_bcast<0x55>(a);
                float ag = dpp_bcast<0xAA>(a);
                float ao = dpp_bcast<0xFF>(a);
                c1 = fmaf(af, c1, ai * ag);
                float h1n = ao * tanhf_f(c1);            // Y[s-1]
                float hpart = __shfl_xor(h1n, 4);        // partner unit u+1
                if ((q & 7) == 0) h1p[pn][u >> 1] = pack_h2(h1n, hpart);
                if ((q & 3) == 1) h1h[(s - 1) * HID + u] = h1n;
            }
            asm volatile("s_waitcnt lgkmcnt(0)" ::: "memory");
            __builtin_amdgcn_s_barrier();
            asm volatile("" ::: "memory");
        }
    }
}

// ---------------------------------------------------------------------------
// Kernel 3a/3b: column-wise min/max of oldh (64 cols x 8192 rows)
// ---------------------------------------------------------------------------
__global__ __launch_bounds__(256) void k_minmax1(
    const float* __restrict__ oldh, float* __restrict__ pmn, float* __restrict__ pmx)
{
    const int t = threadIdx.x, b = blockIdx.x;
    float vmn = FLT_MAX, vmx = -FLT_MAX;
    for (int i = t; i < 128 * HID; i += 256) {
        float v = oldh[b * 128 * HID + i];
        vmn = fminf(vmn, v); vmx = fmaxf(vmx, v);
    }
    __shared__ float smn[256], smx[256];
    smn[t] = vmn; smx[t] = vmx;
    __syncthreads();
    if (t < 64) {
        float m0 = fminf(fminf(smn[t], smn[t + 64]), fminf(smn[t + 128], smn[t + 192]));
        float m1 = fmaxf(fmaxf(smx[t], smx[t + 64]), fmaxf(smx[t + 128], smx[t + 192]));
        pmn[b * 64 + t] = m0; pmx[b * 64 + t] = m1;
    }
}

__global__ __launch_bounds__(256) void k_minmax2(
    const float* __restrict__ pmn, const float* __restrict__ pmx,
    float* __restrict__ mn, float* __restrict__ mx)
{
    const int t = threadIdx.x, col = t & 63, chunk = t >> 6;
    float vmn = FLT_MAX, vmx = -FLT_MAX;
    for (int r = chunk * 16; r < chunk * 16 + 16; ++r) {
        vmn = fminf(vmn, pmn[r * 64 + col]);
        vmx = fmaxf(vmx, pmx[r * 64 + col]);
    }
    __shared__ float smn[256], smx[256];
    smn[t] = vmn; smx[t] = vmx;
    __syncthreads();
    if (t < 64) {
        mn[t] = fminf(fminf(smn[t], smn[t + 64]), fminf(smn[t + 128], smn[t + 192]));
        mx[t] = fmaxf(fmaxf(smx[t], smx[t + 64]), fmaxf(smx[t + 128], smx[t + 192]));
    }
}

// ---------------------------------------------------------------------------
// Kernel 4: per-row head + HPM MLP fwd + closed-form VJP. 1 wave per row.
// ---------------------------------------------------------------------------
__global__ __launch_bounds__(256) void k_finalize(
    const float* __restrict__ h1h, const float* __restrict__ oldh,
    const float* __restrict__ x,
    const float* __restrict__ Wlin, const float* __restrict__ blin,
    const float* __restrict__ Wh1,  const float* __restrict__ bh1,
    const float* __restrict__ Wh2,  const float* __restrict__ bh2,
    const float* __restrict__ mn,   const float* __restrict__ mx,
    float* __restrict__ dout)
{
    float* out_o = dout;                          // [SEQ][10]
    float* out_F = dout + SEQ * OUTW;             // [SEQ][180]
    float* out_A = dout + SEQ * (OUTW + INW);     // [SEQ][318]

    const int wave = threadIdx.x >> 6, lane = threadIdx.x & 63;
    const int row  = blockIdx.x * 4 + wave;

    __shared__ float Xs[4][XW + 2];
    __shared__ float h1sh[4][HID];

    h1sh[wave][lane] = h1h[row * HID + lane];
    float mnv = mn[lane], mxv = mx[lane];
    Xs[wave][254 + lane] = (oldh[row * HID + lane] - mnv) * frcp(mxv - mnv + 1e-6f);
    Xs[wave][10 + lane]  = 0.0f;
    for (int c = lane; c < INW; c += 64) Xs[wave][74 + c] = x[row * INW + c];
    __syncthreads();

    if (lane < OUTW) {
        float o = blin[lane];
#pragma unroll
        for (int k = 0; k < HID; ++k) o += Wlin[lane * HID + k] * h1sh[wave][k];
        Xs[wave][lane] = o;
        out_o[row * OUTW + lane] = o;
    }
    __syncthreads();

    float z0 = 0.f, z1 = 0.f, s0 = 0.f, s1 = 0.f;
    for (int c = lane; c < XW; c += 64) {
        float xv = Xs[wave][c];
        z0 += xv * Wh1[c];
        z1 += xv * Wh1[XW + c];
    }
    for (int j = lane; j < INW; j += 64) {
        s0 += Wh2[j * 2 + 0];
        s1 += Wh2[j * 2 + 1];
    }
#pragma unroll
    for (int off = 32; off; off >>= 1) {
        z0 += __shfl_xor(z0, off); z1 += __shfl_xor(z1, off);
        s0 += __shfl_xor(s0, off); s1 += __shfl_xor(s1, off);
    }
    const float t0 = tanhf_f(z0 + bh1[0]);
    const float t1 = tanhf_f(z1 + bh1[1]);
    const float a0 = -s0 * (1.0f - t0 * t0);
    const float a1 = -s1 * (1.0f - t1 * t1);

    for (int c = lane; c < INW; c += 64)
        out_F[row * INW + c] = -(t0 * Wh2[c * 2 + 0] + t1 * Wh2[c * 2 + 1] + bh2[c]);
    for (int c = lane; c < XW; c += 64)
        out_A[row * XW + c] = a0 * Wh1[c] + a1 * Wh1[XW + c];
}

// ---------------------------------------------------------------------------
extern "C" void kernel_launch(void* const* d_in, const int* in_sizes, int n_in,
                              void* d_out, int out_size, void* d_ws, size_t ws_size,
                              hipStream_t stream)
{
    const float* input = (const float*)d_in[0];
    const float* Wih0  = (const float*)d_in[1];
    const float* Whh0  = (const float*)d_in[2];
    const float* bih0  = (const float*)d_in[3];
    const float* bhh0  = (const float*)d_in[4];
    const float* Wih1  = (const float*)d_in[5];
    const float* Whh1  = (const float*)d_in[6];
    const float* bih1  = (const float*)d_in[7];
    const float* bhh1  = (const float*)d_in[8];
    const float* Wlin  = (const float*)d_in[9];
    const float* blin  = (const float*)d_in[10];
    const float* Wh1   = (const float*)d_in[11];
    const float* bh1   = (const float*)d_in[12];
    const float* Wh2   = (const float*)d_in[13];
    const float* bh2   = (const float*)d_in[14];

    float* ws   = (float*)d_ws;
    float* pre  = ws;                         // SEQ*G4
    float* oldh = pre  + SEQ * G4;            // SEQ*HID
    float* h1h  = oldh + SEQ * HID;           // SEQ*HID
    float* pmn  = h1h  + SEQ * HID;           // 64*64
    float* pmx  = pmn  + 64 * 64;             // 64*64
    float* mn   = pmx  + 64 * 64;             // 64
    float* mx   = mn   + 64;                  // 64
    uint32* w0h  = (uint32*)(mx + 64);        // G4*32 packed half2
    uint32* w1ah = w0h  + G4 * 32;
    uint32* w1bh = w1ah + G4 * 32;
    float* out  = (float*)d_out;

    hipLaunchKernelGGL(k_packw, dim3(96), dim3(256), 0, stream,
                       Whh0, Wih1, Whh1, w0h, w1ah, w1bh);
    hipLaunchKernelGGL(k_precompute, dim3(SEQ / PRE_TS), dim3(256), 0, stream,
                       input, Wih0, bih0, bhh0, pre);
    hipLaunchKernelGGL(k_lstm_seq, dim3(1), dim3(512), 0, stream,
                       pre, w0h, w1ah, w1bh, bih1, bhh1, oldh, h1h);
    hipLaunchKernelGGL(k_minmax1, dim3(64), dim3(256), 0, stream, oldh, pmn, pmx);
    hipLaunchKernelGGL(k_minmax2, dim3(1), dim3(256), 0, stream, pmn, pmx, mn, mx);
    hipLaunchKernelGGL(k_finalize, dim3(SEQ / 4), dim3(256), 0, stream,
                       h1h, oldh, input, Wlin, blin, Wh1, bh1, Wh2, bh2, mn, mx, out);
}